// Round 7
// baseline (249.966 us; speedup 1.0000x reference)
//
#include <hip/hip_runtime.h>
#include <hip/hip_bf16.h>

// MultiHeadAttention: B=2, S=2048, D=1024, H=16, DK=64
// Round 15: fix R14's proj_qkv vmcnt-ordering regression. R14 issued the
// next-tile W-DMAs BEFORE the f32 X register loads; PWRITEX (depends on the
// x-loads = newest VMEM) forced s_waitcnt vmcnt(0) mid-iteration, draining
// the next-tile DMAs too -> pipeline fully serialized (proj 69us, all pipes
// ~14%). R15 swaps issue order (PLOADX first, PSTAGE_A second) so the
// dependency wait is vmcnt(2) and the DMAs stay in flight until the barrier
// (the proven R13 schedule + 4 extra loads sharing the same drain point).
// Everything else identical to R14.
// Workspace: Wcat@0(6M) Wob@6 mb@8 qhd@9 khd@17 vtd@25 oc@33 (41 MB).

using bf16x8 = __attribute__((ext_vector_type(8))) short;
using f32x4  = __attribute__((ext_vector_type(4))) float;
using f32x16 = __attribute__((ext_vector_type(16))) float;

constexpr int Bc = 2, Sc = 2048, Dc = 1024, Hc = 16, DKc = 64;
constexpr int Mc = Bc * Sc;  // 4096
#define QSCALE 0.18033688011112042f  // log2(e)/sqrt(DK), folded into Q proj

__device__ __forceinline__ void lds_load16(const void* g, void* l) {
  __builtin_amdgcn_global_load_lds(
      (const __attribute__((address_space(1))) unsigned int*)g,
      (__attribute__((address_space(3))) unsigned int*)l, 16, 0, 0);
}

#if __has_builtin(__builtin_amdgcn_exp2f)
__device__ __forceinline__ float exp2_fast(float x) { return __builtin_amdgcn_exp2f(x); }
#else
__device__ __forceinline__ float exp2_fast(float x) {
  float r;
  asm("v_exp_f32 %0, %1\n\ts_nop 0" : "=v"(r) : "v"(x));
  return r;
}
#endif

// pack two f32 to bf16x2 word (RNE) via HW cvt
__device__ __forceinline__ unsigned cvt_pk_bf16(float lo, float hi) {
  unsigned r;
  asm("v_cvt_pk_bf16_f32 %0, %1, %2" : "=v"(r) : "v"(lo), "v"(hi));
  return r;
}

// in-place half-swap: a' = [a.lo | b.lo(from lane-32)], b' = [a.hi | b.hi]
#define PSWAP(A, B) \
  asm volatile("v_permlane32_swap_b32 %0, %1" : "+v"(A), "+v"(B))

// RNE pack (epilogues + casts)
__device__ __forceinline__ unsigned pack2bf(float a, float b) {
  union { __hip_bfloat16 h; unsigned short s; } ua, ub;
  ua.h = __float2bfloat16(a);
  ub.h = __float2bfloat16(b);
  return (unsigned)ua.s | ((unsigned)ub.s << 16);
}

// ---------------- prep: W casts + mask pack (vectorized) ----------------
__global__ void prep(const int* __restrict__ mask,
                     const float* __restrict__ Wq, const float* __restrict__ Wk,
                     const float* __restrict__ Wv, const float* __restrict__ Wo,
                     char* __restrict__ ws) {
  const size_t MB = 1024 * 1024;
  int blk = blockIdx.x;
  int tid = threadIdx.x;
  if (blk < 2048) {
    int which = blk >> 9;
    int i = (((blk & 511) << 8) + tid) * 8;
    const float* s = which == 0 ? Wq : (which == 1 ? Wk : (which == 2 ? Wv : Wo));
    __hip_bfloat16* d = (__hip_bfloat16*)(ws + (size_t)2 * which * MB);  // Wob @6
    float4 x = *(const float4*)&s[i];
    float4 y = *(const float4*)&s[i + 4];
    uint4 pk = {pack2bf(x.x, x.y), pack2bf(x.z, x.w),
                pack2bf(y.x, y.y), pack2bf(y.z, y.w)};
    *(uint4*)&d[i] = pk;
  } else {
    int blkm = blk - 2048;
    int i0 = ((blkm << 8) + tid) * 4;
    uint4 m = *(const uint4*)&mask[i0];
    unsigned nib = (m.x != 0 ? 1u : 0u) | (m.y != 0 ? 2u : 0u) |
                   (m.z != 0 ? 4u : 0u) | (m.w != 0 ? 8u : 0u);
    unsigned long long w = (unsigned long long)nib << (4 * (tid & 15));
    w |= __shfl_xor(w, 1);
    w |= __shfl_xor(w, 2);
    w |= __shfl_xor(w, 4);
    w |= __shfl_xor(w, 8);
    if ((tid & 15) == 0)
      ((unsigned long long*)(ws + 8 * MB))[(blkm << 4) + (tid >> 4)] = w;
  }
}

// ---------------- fused QKV projection (BK=32 dbuf, f32-X reg-staged) -----
// A = Wcat (features) via global_load_lds; B = X (f32 q/k/v) reg-staged with
// on-the-fly bf16 cvt. ISSUE ORDER: x-loads FIRST so PWRITEX's dependency
// wait is vmcnt(2) and the next-tile DMAs stay in flight to the barrier.
__global__ __launch_bounds__(256, 3) void proj_qkv(
    const float* __restrict__ qf_, const float* __restrict__ kf_,
    const float* __restrict__ vf_, const __hip_bfloat16* __restrict__ Wcat,
    const float* __restrict__ bq, const float* __restrict__ bk,
    const float* __restrict__ bv, __hip_bfloat16* __restrict__ qhd,
    __hip_bfloat16* __restrict__ khd, __hip_bfloat16* __restrict__ vtd) {
  __shared__ __align__(16) __hip_bfloat16 As[2][128 * 32];  // W tiles, 8KB each
  __shared__ __align__(16) __hip_bfloat16 Bs[2][128 * 32];  // X tiles
  const int tid = threadIdx.x;
  const int f = blockIdx.x, g = f >> 3;
  const int m0 = ((f & 7) * 4 + g / 24) * 128;  // s block
  const int n0 = (g % 24) * 128;                // feature block (0..3072)
  const int which = n0 >> 10, nl0 = n0 & 1023;
  const float* X = which == 0 ? qf_ : (which == 1 ? kf_ : vf_);
  const float* bias = which == 0 ? bq : (which == 1 ? bk : bv);
  const int w = tid >> 6, lane = tid & 63, ln = lane & 15, quad = lane >> 4;
  const int rl = w * 32 + (lane >> 2);
  const int sw8 = ((lane & 3) ^ ((lane >> 2) & 3)) * 8;
  const int aoff = (n0 + rl) * 1024 + sw8;
  const int boff = (m0 + rl) * 1024 + sw8;
  char* aDst = (char*)As + w * 2048 + lane * 16;
  char* bDst = (char*)Bs + w * 2048 + lane * 16;
  const int rkq = (quad ^ (ln & 3)) * 16;
  const int rA0 = ((w >> 1) * 64 + ln) * 64 + rkq;   // + i*1024
  const int rB0 = ((w & 1) * 64 + ln) * 64 + rkq;    // + j*1024
  f32x4 acc[4][4] = {};  // [i: feature 16-blk][j: s 16-blk]

#define PSTAGE_A(KO, BI)                                                      \
  {                                                                           \
    lds_load16(&Wcat[aoff + (KO)], aDst + (BI)*8192);                         \
    lds_load16(&Wcat[aoff + 16384 + (KO)], aDst + (BI)*8192 + 1024);          \
  }
// load 2 rows x 8 f32 of X into regs (issued FIRST so they are the oldest
// outstanding VMEM ops; PWRITEX then waits vmcnt(2), not vmcnt(0))
#define PLOADX(KO)                                                            \
  {                                                                           \
    x0 = *(const float4*)&X[boff + (KO)];                                     \
    x1 = *(const float4*)&X[boff + (KO) + 4];                                 \
    x2 = *(const float4*)&X[boff + 16384 + (KO)];                             \
    x3 = *(const float4*)&X[boff + 16384 + (KO) + 4];                         \
  }
// cvt + write the staged rows (byte-identical to the old DMA image)
#define PWRITEX(BI)                                                           \
  {                                                                           \
    union { unsigned u[4]; bf16x8 v; } t0, t1;                                \
    t0.u[0] = pack2bf(x0.x, x0.y); t0.u[1] = pack2bf(x0.z, x0.w);             \
    t0.u[2] = pack2bf(x1.x, x1.y); t0.u[3] = pack2bf(x1.z, x1.w);             \
    t1.u[0] = pack2bf(x2.x, x2.y); t1.u[1] = pack2bf(x2.z, x2.w);             \
    t1.u[2] = pack2bf(x3.x, x3.y); t1.u[3] = pack2bf(x3.z, x3.w);             \
    *(bf16x8*)(bDst + (BI)*8192) = t0.v;                                      \
    *(bf16x8*)(bDst + (BI)*8192 + 1024) = t1.v;                               \
  }

  float4 x0, x1, x2, x3;
  PLOADX(0);        // x-loads first (oldest)
  PSTAGE_A(0, 0);   // DMAs second (stay in flight across PWRITEX)
  PWRITEX(0);
  if (which == 2) {
    for (int kb32 = 0; kb32 < 32; ++kb32) {
      const int bi = kb32 & 1;
      __syncthreads();
      if (kb32 < 31) { PLOADX((kb32 + 1) * 32); PSTAGE_A((kb32 + 1) * 32, bi ^ 1); }
      bf16x8 af[4], bf[4];
#pragma unroll
      for (int i = 0; i < 4; ++i)
        af[i] = *(bf16x8*)((char*)As + bi * 8192 + rA0 + i * 1024);
#pragma unroll
      for (int j = 0; j < 4; ++j)
        bf[j] = *(bf16x8*)((char*)Bs + bi * 8192 + rB0 + j * 1024);
#pragma unroll
      for (int i = 0; i < 4; ++i)
#pragma unroll
        for (int j = 0; j < 4; ++j)  // swapped: A=X -> C rows = s
          acc[i][j] = __builtin_amdgcn_mfma_f32_16x16x32_bf16(bf[j], af[i],
                                                              acc[i][j], 0, 0, 0);
      if (kb32 < 31) PWRITEX(bi ^ 1);
    }
  } else {
    for (int kb32 = 0; kb32 < 32; ++kb32) {
      const int bi = kb32 & 1;
      __syncthreads();
      if (kb32 < 31) { PLOADX((kb32 + 1) * 32); PSTAGE_A((kb32 + 1) * 32, bi ^ 1); }
      bf16x8 af[4], bf[4];
#pragma unroll
      for (int i = 0; i < 4; ++i)
        af[i] = *(bf16x8*)((char*)As + bi * 8192 + rA0 + i * 1024);
#pragma unroll
      for (int j = 0; j < 4; ++j)
        bf[j] = *(bf16x8*)((char*)Bs + bi * 8192 + rB0 + j * 1024);
#pragma unroll
      for (int i = 0; i < 4; ++i)
#pragma unroll
        for (int j = 0; j < 4; ++j)  // A=W -> C rows = features
          acc[i][j] = __builtin_amdgcn_mfma_f32_16x16x32_bf16(af[i], bf[j],
                                                              acc[i][j], 0, 0, 0);
      if (kb32 < 31) PWRITEX(bi ^ 1);
    }
  }

  const int wA = (w >> 1) * 64, wB = (w & 1) * 64;
  if (which == 2) {
#pragma unroll
    for (int i = 0; i < 4; ++i) {
      int nf = nl0 + wA + i * 16 + ln;
      int h = nf >> 6, dk = nf & 63;
      float bb = bias[nf];
#pragma unroll
      for (int j = 0; j < 4; ++j) {
        int sb = m0 + wB + j * 16 + quad * 4;
        int b = sb >> 11, s = sb & 2047;
        float vv[4] = {acc[i][j][0] + bb, acc[i][j][1] + bb,
                       acc[i][j][2] + bb, acc[i][j][3] + bb};
        uint2 pk = {pack2bf(vv[0], vv[1]), pack2bf(vv[2], vv[3])};
        *(uint2*)&vtd[(((size_t)(b * Hc + h) * DKc + dk) * Sc) + s] = pk;
      }
    }
  } else {
#pragma unroll
    for (int i = 0; i < 4; ++i) {
      int nfb = nl0 + wA + i * 16 + quad * 4;
      float4 b4 = *(const float4*)&bias[nfb];
      int h = nfb >> 6, dk0 = nfb & 63;
#pragma unroll
      for (int j = 0; j < 4; ++j) {
        int sg = m0 + wB + j * 16 + ln;
        int b = sg >> 11, s = sg & 2047;
        float vv[4] = {acc[i][j][0] + b4.x, acc[i][j][1] + b4.y,
                       acc[i][j][2] + b4.z, acc[i][j][3] + b4.w};
        if (which == 0) {
          uint2 pk = {pack2bf(vv[0] * QSCALE, vv[1] * QSCALE),
                      pack2bf(vv[2] * QSCALE, vv[3] * QSCALE)};
          *(uint2*)&qhd[(((size_t)(b * Hc + h) * Sc + s) * DKc) + dk0] = pk;
        } else {
          uint2 pk = {pack2bf(vv[0], vv[1]), pack2bf(vv[2], vv[3])};
          *(uint2*)&khd[(((size_t)(b * Hc + h) * Sc + s) * DKc) + dk0] = pk;
        }
      }
    }
  }
}

// ---------------- out projection (swapped): Y = oc @ Wo^T + bo ------------
__global__ __launch_bounds__(256, 2) void gemm_out(
    const __hip_bfloat16* __restrict__ X, const __hip_bfloat16* __restrict__ W,
    const float* __restrict__ bias, float* __restrict__ Y) {
  __shared__ __align__(16) __hip_bfloat16 As[2][64 * 64];   // Wo tile
  __shared__ __align__(16) __hip_bfloat16 Bs[2][128 * 64];  // oc tile
  const int tid = threadIdx.x;
  const int f = blockIdx.x, g = f >> 3;
  const int m0 = ((f & 7) * 4 + (g >> 4)) * 128;  // s block
  const int n0 = (g & 15) * 64;                    // feature block
  const int w = tid >> 6, lane = tid & 63, ln = lane & 15, quad = lane >> 4;
  const int wA = (w & 1) * 32, wB = (w >> 1) * 64;
  const int swz = ((lane & 7) ^ (lane >> 3)) * 8;
  const int rk0 = ln * 128 + ((quad ^ (ln & 7)) * 16);
  const int rk1 = ln * 128 + (((quad + 4) ^ (ln & 7)) * 16);
  const int aoff = (n0 + w * 16 + (lane >> 3)) * 1024 + swz;
  const int boff = (m0 + w * 32 + (lane >> 3)) * 1024 + swz;
  f32x4 acc[2][4] = {};

#define OSTAGE(KO, BI)                                                        \
  {                                                                           \
    _Pragma("unroll") for (int i = 0; i < 2; ++i)                             \
        lds_load16(&W[aoff + i * 8192 + (KO)],                                \
                   (char*)As[BI] + w * 2048 + lane * 16 + i * 1024);          \
    _Pragma("unroll") for (int i = 0; i < 4; ++i)                             \
        lds_load16(&X[boff + i * 8192 + (KO)],                                \
                   (char*)Bs[BI] + w * 4096 + lane * 16 + i * 1024);          \
  }

  OSTAGE(0, 0);
  for (int kb64 = 0; kb64 < 16; ++kb64) {
    const int bi = kb64 & 1;
    __syncthreads();
    if (kb64 + 1 < 16) OSTAGE((kb64 + 1) * 64, bi ^ 1);
    bf16x8 af[2][2], bf[4][2];
#pragma unroll
    for (int i = 0; i < 2; ++i) {
      af[i][0] = *(bf16x8*)((char*)As[bi] + wA * 128 + i * 2048 + rk0);
      af[i][1] = *(bf16x8*)((char*)As[bi] + wA * 128 + i * 2048 + rk1);
    }
#pragma unroll
    for (int j = 0; j < 4; ++j) {
      bf[j][0] = *(bf16x8*)((char*)Bs[bi] + wB * 128 + j * 2048 + rk0);
      bf[j][1] = *(bf16x8*)((char*)Bs[bi] + wB * 128 + j * 2048 + rk1);
    }
#pragma unroll
    for (int i = 0; i < 2; ++i)
#pragma unroll
      for (int j = 0; j < 4; ++j) {
        acc[i][j] = __builtin_amdgcn_mfma_f32_16x16x32_bf16(af[i][0], bf[j][0],
                                                            acc[i][j], 0, 0, 0);
        acc[i][j] = __builtin_amdgcn_mfma_f32_16x16x32_bf16(af[i][1], bf[j][1],
                                                            acc[i][j], 0, 0, 0);
      }
  }
#pragma unroll
  for (int i = 0; i < 2; ++i) {
    int nfb = n0 + wA + i * 16 + quad * 4;
    float4 b4 = *(const float4*)&bias[nfb];
#pragma unroll
    for (int j = 0; j < 4; ++j) {
      int sg = m0 + wB + j * 16 + ln;
      float4 st = {acc[i][j][0] + b4.x, acc[i][j][1] + b4.y,
                   acc[i][j][2] + b4.z, acc[i][j][3] + b4.w};
      *(float4*)&Y[(size_t)sg * Dc + nfb] = st;
    }
  }
}

// ---------------- flash attention (32x32, in-register P) ------------------
__global__ __launch_bounds__(256, 2) void flash_attn(
    const __hip_bfloat16* __restrict__ qh, const __hip_bfloat16* __restrict__ kh,
    const __hip_bfloat16* __restrict__ vt, const uint2* __restrict__ mb2,
    __hip_bfloat16* __restrict__ oc) {
  __shared__ __align__(16) char L[32768];  // K bufs 2x8K @0, V^T bufs 2x8K @16384
  const int tid = threadIdx.x;
  const int f = blockIdx.x, g = f >> 3;
  const int bh = (f & 7) * 4 + (g >> 4);  // 0..31
  const int q0 = (g & 15) * 128;
  const int b = bh >> 4, h = bh & 15;
  const int w = tid >> 6, lane = tid & 63, l31 = lane & 31, hi = lane >> 5;
  const size_t base = (size_t)bh * Sc * DKc;
  const __hip_bfloat16* khb = kh + base;
  const __hip_bfloat16* vtb = vt + base;
  const int qglob = q0 + w * 32 + l31;

  // Q B-fragments: B[d = dt*16 + hi*8 + j][q = l31]
  bf16x8 qf[4];
#pragma unroll
  for (int dt = 0; dt < 4; ++dt)
    qf[dt] = *(const bf16x8*)&qh[base + (size_t)qglob * 64 + dt * 16 + hi * 8];

  bf16x8 onesA;
#pragma unroll
  for (int i = 0; i < 8; ++i) onesA[i] = (short)0x3F80;  // bf16 1.0

  // DMA: linear LDS dest, pre-swizzled global src (slot s' holds d/k-slot
  // s'^(row&7)). K tile [64k][64d]; V^T tile [64d][64k].
  const int trow = tid >> 3, tcol = tid & 7;
  const int kbase = trow * 64 + ((tcol ^ (trow & 7)) * 8);    // elements
  const int vbase = trow * 2048 + ((tcol ^ (trow & 7)) * 8);  // elements
  char* Ld = L + tid * 16;

  const int rowb = l31 * 128;
  const int xs = lane & 7;

  f32x16 Oacc0 = {}, Oacc1 = {}, lacc = {};

#define STAGE(BI, T)                                                          \
  {                                                                           \
    lds_load16(khb + kbase + (T)*4096,        Ld + (BI)*8192);                \
    lds_load16(khb + kbase + (T)*4096 + 2048, Ld + (BI)*8192 + 4096);         \
    lds_load16(vtb + vbase + (T)*64,          Ld + 16384 + (BI)*8192);        \
    lds_load16(vtb + vbase + (T)*64 + 65536,  Ld + 16384 + (BI)*8192 + 4096); \
  }

  // process one 32-k subtile: QK^T (4 mfma) -> masked exp2 -> cvt_pk+permlane
  // -> pb[2*SUB], pb[2*SUB+1] (B-frags for PV k16-tiles)
#define PROC_SUB(BOFF, SUB, MW)                                               \
  {                                                                           \
    bf16x8 kf0 = *(bf16x8*)(L + (BOFF) + (SUB)*4096 + rowb + (((0 + hi) ^ xs) * 16)); \
    bf16x8 kf1 = *(bf16x8*)(L + (BOFF) + (SUB)*4096 + rowb + (((2 + hi) ^ xs) * 16)); \
    bf16x8 kf2 = *(bf16x8*)(L + (BOFF) + (SUB)*4096 + rowb + (((4 + hi) ^ xs) * 16)); \
    bf16x8 kf3 = *(bf16x8*)(L + (BOFF) + (SUB)*4096 + rowb + (((6 + hi) ^ xs) * 16)); \
    f32x16 c = {};                                                            \
    __builtin_amdgcn_s_setprio(1);                                            \
    c = __builtin_amdgcn_mfma_f32_32x32x16_bf16(kf0, qf[0], c, 0, 0, 0);      \
    c = __builtin_amdgcn_mfma_f32_32x32x16_bf16(kf1, qf[1], c, 0, 0, 0);      \
    c = __builtin_amdgcn_mfma_f32_32x32x16_bf16(kf2, qf[2], c, 0, 0, 0);      \
    c = __builtin_amdgcn_mfma_f32_32x32x16_bf16(kf3, qf[3], c, 0, 0, 0);      \
    __builtin_amdgcn_s_setprio(0);                                            \
    unsigned shm = (MW) >> (hi * 4);                                          \
    float p[16];                                                              \
    _Pragma("unroll") for (int r = 0; r < 16; ++r) {                          \
      unsigned tg = shm >> (8 * (r >> 2));                                    \
      float e = exp2_fast(c[r]);                                              \
      p[r] = (tg & (1u << (r & 3))) ? e : 0.f;                                \
    }                                                                         \
    unsigned w0 = cvt_pk_bf16(p[0], p[1]),   w1 = cvt_pk_bf16(p[2], p[3]);    \
    unsigned w2 = cvt_pk_bf16(p[4], p[5]),   w3 = cvt_pk_bf16(p[6], p[7]);    \
    unsigned w4 = cvt_pk_bf16(p[8], p[9]),   w5 = cvt_pk_bf16(p[10], p[11]);  \
    unsigned w6 = cvt_pk_bf16(p[12], p[13]), w7 = cvt_pk_bf16(p[14], p[15]);  \
    PSWAP(w0, w2); PSWAP(w1, w3); PSWAP(w4, w6); PSWAP(w5, w7);               \
    { union { unsigned u[4]; bf16x8 v; } t;                                   \
      t.u[0] = w0; t.u[1] = w1; t.u[2] = w2; t.u[3] = w3;                     \
      pb[(SUB)*2] = t.v; }                                                    \
    { union { unsigned u[4]; bf16x8 v; } t;                                   \
      t.u[0] = w4; t.u[1] = w5; t.u[2] = w6; t.u[3] = w7;                     \
      pb[(SUB)*2 + 1] = t.v; }                                                \
  }

  const uint2* mrow = mb2 + (size_t)qglob * 32;
  uint2 mbC = mrow[0];
  STAGE(0, 0);

  for (int t = 0; t < 32; ++t) {
    __syncthreads();  // drains STAGE(t); all waves done reading buf t-1
    uint2 mbN = mbC;
    if (t < 31) {
      mbN = mrow[t + 1];
      STAGE((t + 1) & 1, t + 1);  // full-tile pipeline distance (R8 pattern)
    }
    const int boff = (t & 1) * 8192;

    bf16x8 pb[4];
    PROC_SUB(boff, 0, mbC.x);
    PROC_SUB(boff, 1, mbC.y);

    // PV + l: A = V^T frag [d = do*32+l31][k = kt*16+hi*8+j], B = pb[kt]
    __builtin_amdgcn_s_setprio(1);
#pragma unroll
    for (int kt = 0; kt < 4; ++kt) {
      lacc = __builtin_amdgcn_mfma_f32_32x32x16_bf16(onesA, pb[kt], lacc, 0, 0, 0);
      bf16x8 vf0 = *(bf16x8*)(L + 16384 + boff + rowb + (((kt * 2 + hi) ^ xs) * 16));
      bf16x8 vf1 = *(bf16x8*)(L + 16384 + boff + 4096 + rowb + (((kt * 2 + hi) ^ xs) * 16));
      Oacc0 = __builtin_amdgcn_mfma_f32_32x32x16_bf16(vf0, pb[kt], Oacc0, 0, 0, 0);
      Oacc1 = __builtin_amdgcn_mfma_f32_32x32x16_bf16(vf1, pb[kt], Oacc1, 0, 0, 0);
    }
    __builtin_amdgcn_s_setprio(0);
    mbC = mbN;
  }

  // ---- epilogue: all state in registers; direct packed stores ----
  float linv = 1.f / fmaxf(lacc[0], 1e-30f);
  const size_t obase = (size_t)(b * Sc + qglob) * Dc + h * 64;
#pragma unroll
  for (int gq = 0; gq < 4; ++gq) {
    int d0 = gq * 8 + hi * 4;
    uint2 pk0 = {pack2bf(Oacc0[4 * gq] * linv, Oacc0[4 * gq + 1] * linv),
                 pack2bf(Oacc0[4 * gq + 2] * linv, Oacc0[4 * gq + 3] * linv)};
    *(uint2*)&oc[obase + d0] = pk0;
    uint2 pk1 = {pack2bf(Oacc1[4 * gq] * linv, Oacc1[4 * gq + 1] * linv),
                 pack2bf(Oacc1[4 * gq + 2] * linv, Oacc1[4 * gq + 3] * linv)};
    *(uint2*)&oc[obase + 32 + d0] = pk1;
  }
#undef STAGE
#undef PROC_SUB
}

extern "C" void kernel_launch(void* const* d_in, const int* in_sizes, int n_in,
                              void* d_out, int out_size, void* d_ws, size_t ws_size,
                              hipStream_t stream) {
  const float* q  = (const float*)d_in[0];
  const float* k  = (const float*)d_in[1];
  const float* v  = (const float*)d_in[2];
  const int* mask = (const int*)d_in[3];
  const float* Wq = (const float*)d_in[4];
  const float* bq = (const float*)d_in[5];
  const float* Wk = (const float*)d_in[6];
  const float* bk = (const float*)d_in[7];
  const float* Wv = (const float*)d_in[8];
  const float* bv = (const float*)d_in[9];
  const float* Wo = (const float*)d_in[10];
  const float* bo = (const float*)d_in[11];

  char* ws = (char*)d_ws;
  const size_t MB = 1024 * 1024;
  __hip_bfloat16* Wcat = (__hip_bfloat16*)(ws + 0 * MB);   // Wq|Wk|Wv (6 MB)
  __hip_bfloat16* Wob  = (__hip_bfloat16*)(ws + 6 * MB);   // 2 MB
  uint2*          mb2  = (uint2*)(ws + 8 * MB);            // 0.5 MB
  __hip_bfloat16* qhd  = (__hip_bfloat16*)(ws + 9 * MB);
  __hip_bfloat16* khd  = (__hip_bfloat16*)(ws + 17 * MB);
  __hip_bfloat16* vtd  = (__hip_bfloat16*)(ws + 25 * MB);
  __hip_bfloat16* oc   = (__hip_bfloat16*)(ws + 33 * MB);

  prep<<<6144, 256, 0, stream>>>(mask, Wq, Wk, Wv, Wo, ws);
  proj_qkv<<<768, 256, 0, stream>>>(q, k, v, Wcat, bq, bk, bv, qhd, khd, vtd);
  flash_attn<<<512, 256, 0, stream>>>(qhd, khd, vtd, mb2, oc);
  gemm_out<<<512, 256, 0, stream>>>(oc, Wob, bo, (float*)d_out);
}

// Round 8
// 238.546 us; speedup vs baseline: 1.0479x; 1.0479x over previous
//
#include <hip/hip_runtime.h>
#include <hip/hip_bf16.h>

// MultiHeadAttention: B=2, S=2048, D=1024, H=16, DK=64
// Round 16: revert to the R13 pipeline. The fused f32-X proj (R14/R15) was
// condemned: both variants ~70us at 13% MfmaUtil (vs <59 for the DMA-staged
// form), WRITE_SIZE +10MB (spill), and R13<->R14 deltas showed the fusion
// only relocated prep's ~11us into proj. Kept from R14: the x8-vectorized
// prep (8 f32/thread casts, uint4 mask pack + 16-lane shfl-or), 32768 ->
// 12288 blocks. proj_qkv / flash_attn / gemm_out are byte-identical to R13.
// Decomposition note: known dispatches sum to ~165us of the ~244 total ->
// ~80us is fixed launch/restore overhead no kernel edit touches.
// Workspace: qb@0 kb@8 vb@16 Wcat@24(6M) Wob@30 mb@32 qhd@33 khd@41
//            vtd@49 oc@57  (MiB offsets)

using bf16x8 = __attribute__((ext_vector_type(8))) short;
using f32x4  = __attribute__((ext_vector_type(4))) float;
using f32x16 = __attribute__((ext_vector_type(16))) float;

constexpr int Bc = 2, Sc = 2048, Dc = 1024, Hc = 16, DKc = 64;
constexpr int Mc = Bc * Sc;  // 4096
#define QSCALE 0.18033688011112042f  // log2(e)/sqrt(DK), folded into Q proj

__device__ __forceinline__ void lds_load16(const void* g, void* l) {
  __builtin_amdgcn_global_load_lds(
      (const __attribute__((address_space(1))) unsigned int*)g,
      (__attribute__((address_space(3))) unsigned int*)l, 16, 0, 0);
}

#if __has_builtin(__builtin_amdgcn_exp2f)
__device__ __forceinline__ float exp2_fast(float x) { return __builtin_amdgcn_exp2f(x); }
#else
__device__ __forceinline__ float exp2_fast(float x) {
  float r;
  asm("v_exp_f32 %0, %1\n\ts_nop 0" : "=v"(r) : "v"(x));
  return r;
}
#endif

// pack two f32 to bf16x2 word (RNE) via HW cvt
__device__ __forceinline__ unsigned cvt_pk_bf16(float lo, float hi) {
  unsigned r;
  asm("v_cvt_pk_bf16_f32 %0, %1, %2" : "=v"(r) : "v"(lo), "v"(hi));
  return r;
}

// in-place half-swap: a' = [a.lo | b.lo(from lane-32)], b' = [a.hi | b.hi]
#define PSWAP(A, B) \
  asm volatile("v_permlane32_swap_b32 %0, %1" : "+v"(A), "+v"(B))

// RNE pack (epilogues + casts)
__device__ __forceinline__ unsigned pack2bf(float a, float b) {
  union { __hip_bfloat16 h; unsigned short s; } ua, ub;
  ua.h = __float2bfloat16(a);
  ub.h = __float2bfloat16(b);
  return (unsigned)ua.s | ((unsigned)ub.s << 16);
}

// ---------------- prep: fused casts + mask pack (x8 vectorized) -----------
// blk <  6144: q/k/v cast, 8 f32/thread (which = blk>>11)
// blk <  8192: W cast, 8 f32/thread (which = (blk-6144)>>9)
// blk >= 8192: mask pack, uint4/thread -> nibble -> 16-lane shfl-or -> u64
__global__ void prep(const float* __restrict__ q, const float* __restrict__ k,
                     const float* __restrict__ v, const int* __restrict__ mask,
                     const float* __restrict__ Wq, const float* __restrict__ Wk,
                     const float* __restrict__ Wv, const float* __restrict__ Wo,
                     char* __restrict__ ws) {
  const size_t MB = 1024 * 1024;
  int blk = blockIdx.x;
  int tid = threadIdx.x;
  if (blk < 6144) {
    int which = blk >> 11;
    int i = (((blk & 2047) << 8) + tid) * 8;
    const float* s = which == 0 ? q : (which == 1 ? k : v);
    __hip_bfloat16* d = (__hip_bfloat16*)(ws + (size_t)which * 8 * MB);
    float4 x = *(const float4*)&s[i];
    float4 y = *(const float4*)&s[i + 4];
    uint4 pk = {pack2bf(x.x, x.y), pack2bf(x.z, x.w),
                pack2bf(y.x, y.y), pack2bf(y.z, y.w)};
    *(uint4*)&d[i] = pk;
  } else if (blk < 8192) {
    int bb = blk - 6144;
    int which = bb >> 9;
    int i = (((bb & 511) << 8) + tid) * 8;
    const float* s = which == 0 ? Wq : (which == 1 ? Wk : (which == 2 ? Wv : Wo));
    __hip_bfloat16* d = which < 3 ? (__hip_bfloat16*)(ws + (24 + 2 * which) * MB)
                                  : (__hip_bfloat16*)(ws + 30 * MB);
    float4 x = *(const float4*)&s[i];
    float4 y = *(const float4*)&s[i + 4];
    uint4 pk = {pack2bf(x.x, x.y), pack2bf(x.z, x.w),
                pack2bf(y.x, y.y), pack2bf(y.z, y.w)};
    *(uint4*)&d[i] = pk;
  } else {
    int blkm = blk - 8192;
    int i0 = ((blkm << 8) + tid) * 4;
    uint4 m = *(const uint4*)&mask[i0];
    unsigned nib = (m.x != 0 ? 1u : 0u) | (m.y != 0 ? 2u : 0u) |
                   (m.z != 0 ? 4u : 0u) | (m.w != 0 ? 8u : 0u);
    unsigned long long w = (unsigned long long)nib << (4 * (tid & 15));
    w |= __shfl_xor(w, 1);
    w |= __shfl_xor(w, 2);
    w |= __shfl_xor(w, 4);
    w |= __shfl_xor(w, 8);
    if ((tid & 15) == 0)
      ((unsigned long long*)(ws + 32 * MB))[(blkm << 4) + (tid >> 4)] = w;
  }
}

// ---------------- fused QKV projection (BK=32 dbuf, DMA both sides) -------
// A = Wcat (features), B = X (s). Q/K: mfma(A=W,B=X) -> C col=s,row=feat ->
// packed dk stores. V: mfma(A=X,B=W) -> C col=feat,row=s -> packed s stores
// into V^T [B,H,DK,S]. flat grid 768, XCD swizzle, 3 blocks/CU.
__global__ __launch_bounds__(256, 3) void proj_qkv(
    const __hip_bfloat16* __restrict__ qb, const __hip_bfloat16* __restrict__ kb,
    const __hip_bfloat16* __restrict__ vb, const __hip_bfloat16* __restrict__ Wcat,
    const float* __restrict__ bq, const float* __restrict__ bk,
    const float* __restrict__ bv, __hip_bfloat16* __restrict__ qhd,
    __hip_bfloat16* __restrict__ khd, __hip_bfloat16* __restrict__ vtd) {
  __shared__ __align__(16) __hip_bfloat16 As[2][128 * 32];  // W tiles, 8KB each
  __shared__ __align__(16) __hip_bfloat16 Bs[2][128 * 32];  // X tiles
  const int tid = threadIdx.x;
  const int f = blockIdx.x, g = f >> 3;
  const int m0 = ((f & 7) * 4 + g / 24) * 128;  // s block
  const int n0 = (g % 24) * 128;                // feature block (0..3072)
  const int which = n0 >> 10, nl0 = n0 & 1023;
  const __hip_bfloat16* X = which == 0 ? qb : (which == 1 ? kb : vb);
  const float* bias = which == 0 ? bq : (which == 1 ? bk : bv);
  const int w = tid >> 6, lane = tid & 63, ln = lane & 15, quad = lane >> 4;
  const int rl = w * 32 + (lane >> 2);
  const int sw8 = ((lane & 3) ^ ((lane >> 2) & 3)) * 8;
  const int aoff = (n0 + rl) * 1024 + sw8;
  const int boff = (m0 + rl) * 1024 + sw8;
  char* aDst = (char*)As + w * 2048 + lane * 16;
  char* bDst = (char*)Bs + w * 2048 + lane * 16;
  const int rkq = (quad ^ (ln & 3)) * 16;
  const int rA0 = ((w >> 1) * 64 + ln) * 64 + rkq;   // + i*1024
  const int rB0 = ((w & 1) * 64 + ln) * 64 + rkq;    // + j*1024
  f32x4 acc[4][4] = {};  // [i: feature 16-blk][j: s 16-blk]

#define PSTAGE(KO, BI)                                                        \
  {                                                                           \
    lds_load16(&Wcat[aoff + (KO)], aDst + (BI)*8192);                         \
    lds_load16(&Wcat[aoff + 16384 + (KO)], aDst + (BI)*8192 + 1024);          \
    lds_load16(&X[boff + (KO)], bDst + (BI)*8192);                            \
    lds_load16(&X[boff + 16384 + (KO)], bDst + (BI)*8192 + 1024);             \
  }

  PSTAGE(0, 0);
  if (which == 2) {
    for (int kb32 = 0; kb32 < 32; ++kb32) {
      const int bi = kb32 & 1;
      __syncthreads();
      if (kb32 < 31) PSTAGE((kb32 + 1) * 32, bi ^ 1);
      bf16x8 af[4], bf[4];
#pragma unroll
      for (int i = 0; i < 4; ++i)
        af[i] = *(bf16x8*)((char*)As + bi * 8192 + rA0 + i * 1024);
#pragma unroll
      for (int j = 0; j < 4; ++j)
        bf[j] = *(bf16x8*)((char*)Bs + bi * 8192 + rB0 + j * 1024);
#pragma unroll
      for (int i = 0; i < 4; ++i)
#pragma unroll
        for (int j = 0; j < 4; ++j)  // swapped: A=X -> C rows = s
          acc[i][j] = __builtin_amdgcn_mfma_f32_16x16x32_bf16(bf[j], af[i],
                                                              acc[i][j], 0, 0, 0);
    }
  } else {
    for (int kb32 = 0; kb32 < 32; ++kb32) {
      const int bi = kb32 & 1;
      __syncthreads();
      if (kb32 < 31) PSTAGE((kb32 + 1) * 32, bi ^ 1);
      bf16x8 af[4], bf[4];
#pragma unroll
      for (int i = 0; i < 4; ++i)
        af[i] = *(bf16x8*)((char*)As + bi * 8192 + rA0 + i * 1024);
#pragma unroll
      for (int j = 0; j < 4; ++j)
        bf[j] = *(bf16x8*)((char*)Bs + bi * 8192 + rB0 + j * 1024);
#pragma unroll
      for (int i = 0; i < 4; ++i)
#pragma unroll
        for (int j = 0; j < 4; ++j)  // A=W -> C rows = features
          acc[i][j] = __builtin_amdgcn_mfma_f32_16x16x32_bf16(af[i], bf[j],
                                                              acc[i][j], 0, 0, 0);
    }
  }

  const int wA = (w >> 1) * 64, wB = (w & 1) * 64;
  if (which == 2) {
#pragma unroll
    for (int i = 0; i < 4; ++i) {
      int nf = nl0 + wA + i * 16 + ln;
      int h = nf >> 6, dk = nf & 63;
      float bb = bias[nf];
#pragma unroll
      for (int j = 0; j < 4; ++j) {
        int sb = m0 + wB + j * 16 + quad * 4;
        int b = sb >> 11, s = sb & 2047;
        float vv[4] = {acc[i][j][0] + bb, acc[i][j][1] + bb,
                       acc[i][j][2] + bb, acc[i][j][3] + bb};
        uint2 pk = {pack2bf(vv[0], vv[1]), pack2bf(vv[2], vv[3])};
        *(uint2*)&vtd[(((size_t)(b * Hc + h) * DKc + dk) * Sc) + s] = pk;
      }
    }
  } else {
#pragma unroll
    for (int i = 0; i < 4; ++i) {
      int nfb = nl0 + wA + i * 16 + quad * 4;
      float4 b4 = *(const float4*)&bias[nfb];
      int h = nfb >> 6, dk0 = nfb & 63;
#pragma unroll
      for (int j = 0; j < 4; ++j) {
        int sg = m0 + wB + j * 16 + ln;
        int b = sg >> 11, s = sg & 2047;
        float vv[4] = {acc[i][j][0] + b4.x, acc[i][j][1] + b4.y,
                       acc[i][j][2] + b4.z, acc[i][j][3] + b4.w};
        if (which == 0) {
          uint2 pk = {pack2bf(vv[0] * QSCALE, vv[1] * QSCALE),
                      pack2bf(vv[2] * QSCALE, vv[3] * QSCALE)};
          *(uint2*)&qhd[(((size_t)(b * Hc + h) * Sc + s) * DKc) + dk0] = pk;
        } else {
          uint2 pk = {pack2bf(vv[0], vv[1]), pack2bf(vv[2], vv[3])};
          *(uint2*)&khd[(((size_t)(b * Hc + h) * Sc + s) * DKc) + dk0] = pk;
        }
      }
    }
  }
}

// ---------------- out projection (swapped): Y = oc @ Wo^T + bo ------------
__global__ __launch_bounds__(256, 2) void gemm_out(
    const __hip_bfloat16* __restrict__ X, const __hip_bfloat16* __restrict__ W,
    const float* __restrict__ bias, float* __restrict__ Y) {
  __shared__ __align__(16) __hip_bfloat16 As[2][64 * 64];   // Wo tile
  __shared__ __align__(16) __hip_bfloat16 Bs[2][128 * 64];  // oc tile
  const int tid = threadIdx.x;
  const int f = blockIdx.x, g = f >> 3;
  const int m0 = ((f & 7) * 4 + (g >> 4)) * 128;  // s block
  const int n0 = (g & 15) * 64;                    // feature block
  const int w = tid >> 6, lane = tid & 63, ln = lane & 15, quad = lane >> 4;
  const int wA = (w & 1) * 32, wB = (w >> 1) * 64;
  const int swz = ((lane & 7) ^ (lane >> 3)) * 8;
  const int rk0 = ln * 128 + ((quad ^ (ln & 7)) * 16);
  const int rk1 = ln * 128 + (((quad + 4) ^ (ln & 7)) * 16);
  const int aoff = (n0 + w * 16 + (lane >> 3)) * 1024 + swz;
  const int boff = (m0 + w * 32 + (lane >> 3)) * 1024 + swz;
  f32x4 acc[2][4] = {};

#define OSTAGE(KO, BI)                                                        \
  {                                                                           \
    _Pragma("unroll") for (int i = 0; i < 2; ++i)                             \
        lds_load16(&W[aoff + i * 8192 + (KO)],                                \
                   (char*)As[BI] + w * 2048 + lane * 16 + i * 1024);          \
    _Pragma("unroll") for (int i = 0; i < 4; ++i)                             \
        lds_load16(&X[boff + i * 8192 + (KO)],                                \
                   (char*)Bs[BI] + w * 4096 + lane * 16 + i * 1024);          \
  }

  OSTAGE(0, 0);
  for (int kb64 = 0; kb64 < 16; ++kb64) {
    const int bi = kb64 & 1;
    __syncthreads();
    if (kb64 + 1 < 16) OSTAGE((kb64 + 1) * 64, bi ^ 1);
    bf16x8 af[2][2], bf[4][2];
#pragma unroll
    for (int i = 0; i < 2; ++i) {
      af[i][0] = *(bf16x8*)((char*)As[bi] + wA * 128 + i * 2048 + rk0);
      af[i][1] = *(bf16x8*)((char*)As[bi] + wA * 128 + i * 2048 + rk1);
    }
#pragma unroll
    for (int j = 0; j < 4; ++j) {
      bf[j][0] = *(bf16x8*)((char*)Bs[bi] + wB * 128 + j * 2048 + rk0);
      bf[j][1] = *(bf16x8*)((char*)Bs[bi] + wB * 128 + j * 2048 + rk1);
    }
#pragma unroll
    for (int i = 0; i < 2; ++i)
#pragma unroll
      for (int j = 0; j < 4; ++j) {
        acc[i][j] = __builtin_amdgcn_mfma_f32_16x16x32_bf16(af[i][0], bf[j][0],
                                                            acc[i][j], 0, 0, 0);
        acc[i][j] = __builtin_amdgcn_mfma_f32_16x16x32_bf16(af[i][1], bf[j][1],
                                                            acc[i][j], 0, 0, 0);
      }
  }
#pragma unroll
  for (int i = 0; i < 2; ++i) {
    int nfb = n0 + wA + i * 16 + quad * 4;
    float4 b4 = *(const float4*)&bias[nfb];
#pragma unroll
    for (int j = 0; j < 4; ++j) {
      int sg = m0 + wB + j * 16 + ln;
      float4 st = {acc[i][j][0] + b4.x, acc[i][j][1] + b4.y,
                   acc[i][j][2] + b4.z, acc[i][j][3] + b4.w};
      *(float4*)&Y[(size_t)sg * Dc + nfb] = st;
    }
  }
}

// ---------------- flash attention (32x32, in-register P) ------------------
__global__ __launch_bounds__(256, 2) void flash_attn(
    const __hip_bfloat16* __restrict__ qh, const __hip_bfloat16* __restrict__ kh,
    const __hip_bfloat16* __restrict__ vt, const uint2* __restrict__ mb2,
    __hip_bfloat16* __restrict__ oc) {
  __shared__ __align__(16) char L[32768];  // K bufs 2x8K @0, V^T bufs 2x8K @16384
  const int tid = threadIdx.x;
  const int f = blockIdx.x, g = f >> 3;
  const int bh = (f & 7) * 4 + (g >> 4);  // 0..31
  const int q0 = (g & 15) * 128;
  const int b = bh >> 4, h = bh & 15;
  const int w = tid >> 6, lane = tid & 63, l31 = lane & 31, hi = lane >> 5;
  const size_t base = (size_t)bh * Sc * DKc;
  const __hip_bfloat16* khb = kh + base;
  const __hip_bfloat16* vtb = vt + base;
  const int qglob = q0 + w * 32 + l31;

  // Q B-fragments: B[d = dt*16 + hi*8 + j][q = l31]
  bf16x8 qf[4];
#pragma unroll
  for (int dt = 0; dt < 4; ++dt)
    qf[dt] = *(const bf16x8*)&qh[base + (size_t)qglob * 64 + dt * 16 + hi * 8];

  bf16x8 onesA;
#pragma unroll
  for (int i = 0; i < 8; ++i) onesA[i] = (short)0x3F80;  // bf16 1.0

  // DMA: linear LDS dest, pre-swizzled global src (slot s' holds d/k-slot
  // s'^(row&7)). K tile [64k][64d]; V^T tile [64d][64k].
  const int trow = tid >> 3, tcol = tid & 7;
  const int kbase = trow * 64 + ((tcol ^ (trow & 7)) * 8);    // elements
  const int vbase = trow * 2048 + ((tcol ^ (trow & 7)) * 8);  // elements
  char* Ld = L + tid * 16;

  const int rowb = l31 * 128;
  const int xs = lane & 7;

  f32x16 Oacc0 = {}, Oacc1 = {}, lacc = {};

#define STAGE(BI, T)                                                          \
  {                                                                           \
    lds_load16(khb + kbase + (T)*4096,        Ld + (BI)*8192);                \
    lds_load16(khb + kbase + (T)*4096 + 2048, Ld + (BI)*8192 + 4096);         \
    lds_load16(vtb + vbase + (T)*64,          Ld + 16384 + (BI)*8192);        \
    lds_load16(vtb + vbase + (T)*64 + 65536,  Ld + 16384 + (BI)*8192 + 4096); \
  }

  // process one 32-k subtile: QK^T (4 mfma) -> masked exp2 -> cvt_pk+permlane
  // -> pb[2*SUB], pb[2*SUB+1] (B-frags for PV k16-tiles)
#define PROC_SUB(BOFF, SUB, MW)                                               \
  {                                                                           \
    bf16x8 kf0 = *(bf16x8*)(L + (BOFF) + (SUB)*4096 + rowb + (((0 + hi) ^ xs) * 16)); \
    bf16x8 kf1 = *(bf16x8*)(L + (BOFF) + (SUB)*4096 + rowb + (((2 + hi) ^ xs) * 16)); \
    bf16x8 kf2 = *(bf16x8*)(L + (BOFF) + (SUB)*4096 + rowb + (((4 + hi) ^ xs) * 16)); \
    bf16x8 kf3 = *(bf16x8*)(L + (BOFF) + (SUB)*4096 + rowb + (((6 + hi) ^ xs) * 16)); \
    f32x16 c = {};                                                            \
    __builtin_amdgcn_s_setprio(1);                                            \
    c = __builtin_amdgcn_mfma_f32_32x32x16_bf16(kf0, qf[0], c, 0, 0, 0);      \
    c = __builtin_amdgcn_mfma_f32_32x32x16_bf16(kf1, qf[1], c, 0, 0, 0);      \
    c = __builtin_amdgcn_mfma_f32_32x32x16_bf16(kf2, qf[2], c, 0, 0, 0);      \
    c = __builtin_amdgcn_mfma_f32_32x32x16_bf16(kf3, qf[3], c, 0, 0, 0);      \
    __builtin_amdgcn_s_setprio(0);                                            \
    unsigned shm = (MW) >> (hi * 4);                                          \
    float p[16];                                                              \
    _Pragma("unroll") for (int r = 0; r < 16; ++r) {                          \
      unsigned tg = shm >> (8 * (r >> 2));                                    \
      float e = exp2_fast(c[r]);                                              \
      p[r] = (tg & (1u << (r & 3))) ? e : 0.f;                                \
    }                                                                         \
    unsigned w0 = cvt_pk_bf16(p[0], p[1]),   w1 = cvt_pk_bf16(p[2], p[3]);    \
    unsigned w2 = cvt_pk_bf16(p[4], p[5]),   w3 = cvt_pk_bf16(p[6], p[7]);    \
    unsigned w4 = cvt_pk_bf16(p[8], p[9]),   w5 = cvt_pk_bf16(p[10], p[11]);  \
    unsigned w6 = cvt_pk_bf16(p[12], p[13]), w7 = cvt_pk_bf16(p[14], p[15]);  \
    PSWAP(w0, w2); PSWAP(w1, w3); PSWAP(w4, w6); PSWAP(w5, w7);               \
    { union { unsigned u[4]; bf16x8 v; } t;                                   \
      t.u[0] = w0; t.u[1] = w1; t.u[2] = w2; t.u[3] = w3;                     \
      pb[(SUB)*2] = t.v; }                                                    \
    { union { unsigned u[4]; bf16x8 v; } t;                                   \
      t.u[0] = w4; t.u[1] = w5; t.u[2] = w6; t.u[3] = w7;                     \
      pb[(SUB)*2 + 1] = t.v; }                                                \
  }

  const uint2* mrow = mb2 + (size_t)qglob * 32;
  uint2 mbC = mrow[0];
  STAGE(0, 0);

  for (int t = 0; t < 32; ++t) {
    __syncthreads();  // drains STAGE(t); all waves done reading buf t-1
    uint2 mbN = mbC;
    if (t < 31) {
      mbN = mrow[t + 1];
      STAGE((t + 1) & 1, t + 1);  // full-tile pipeline distance (R8 pattern)
    }
    const int boff = (t & 1) * 8192;

    bf16x8 pb[4];
    PROC_SUB(boff, 0, mbC.x);
    PROC_SUB(boff, 1, mbC.y);

    // PV + l: A = V^T frag [d = do*32+l31][k = kt*16+hi*8+j], B = pb[kt]
    __builtin_amdgcn_s_setprio(1);
#pragma unroll
    for (int kt = 0; kt < 4; ++kt) {
      lacc = __builtin_amdgcn_mfma_f32_32x32x16_bf16(onesA, pb[kt], lacc, 0, 0, 0);
      bf16x8 vf0 = *(bf16x8*)(L + 16384 + boff + rowb + (((kt * 2 + hi) ^ xs) * 16));
      bf16x8 vf1 = *(bf16x8*)(L + 16384 + boff + 4096 + rowb + (((kt * 2 + hi) ^ xs) * 16));
      Oacc0 = __builtin_amdgcn_mfma_f32_32x32x16_bf16(vf0, pb[kt], Oacc0, 0, 0, 0);
      Oacc1 = __builtin_amdgcn_mfma_f32_32x32x16_bf16(vf1, pb[kt], Oacc1, 0, 0, 0);
    }
    __builtin_amdgcn_s_setprio(0);
    mbC = mbN;
  }

  // ---- epilogue: all state in registers; direct packed stores ----
  float linv = 1.f / fmaxf(lacc[0], 1e-30f);
  const size_t obase = (size_t)(b * Sc + qglob) * Dc + h * 64;
#pragma unroll
  for (int gq = 0; gq < 4; ++gq) {
    int d0 = gq * 8 + hi * 4;
    uint2 pk0 = {pack2bf(Oacc0[4 * gq] * linv, Oacc0[4 * gq + 1] * linv),
                 pack2bf(Oacc0[4 * gq + 2] * linv, Oacc0[4 * gq + 3] * linv)};
    *(uint2*)&oc[obase + d0] = pk0;
    uint2 pk1 = {pack2bf(Oacc1[4 * gq] * linv, Oacc1[4 * gq + 1] * linv),
                 pack2bf(Oacc1[4 * gq + 2] * linv, Oacc1[4 * gq + 3] * linv)};
    *(uint2*)&oc[obase + 32 + d0] = pk1;
  }
#undef STAGE
#undef PROC_SUB
}

extern "C" void kernel_launch(void* const* d_in, const int* in_sizes, int n_in,
                              void* d_out, int out_size, void* d_ws, size_t ws_size,
                              hipStream_t stream) {
  const float* q  = (const float*)d_in[0];
  const float* k  = (const float*)d_in[1];
  const float* v  = (const float*)d_in[2];
  const int* mask = (const int*)d_in[3];
  const float* Wq = (const float*)d_in[4];
  const float* bq = (const float*)d_in[5];
  const float* Wk = (const float*)d_in[6];
  const float* bk = (const float*)d_in[7];
  const float* Wv = (const float*)d_in[8];
  const float* bv = (const float*)d_in[9];
  const float* Wo = (const float*)d_in[10];
  const float* bo = (const float*)d_in[11];

  char* ws = (char*)d_ws;
  const size_t MB = 1024 * 1024;
  __hip_bfloat16* qb   = (__hip_bfloat16*)(ws + 0 * MB);
  __hip_bfloat16* kb   = (__hip_bfloat16*)(ws + 8 * MB);
  __hip_bfloat16* vb   = (__hip_bfloat16*)(ws + 16 * MB);
  __hip_bfloat16* Wcat = (__hip_bfloat16*)(ws + 24 * MB);  // Wq|Wk|Wv
  __hip_bfloat16* Wob  = (__hip_bfloat16*)(ws + 30 * MB);
  uint2*          mb2  = (uint2*)(ws + 32 * MB);
  __hip_bfloat16* qhd  = (__hip_bfloat16*)(ws + 33 * MB);
  __hip_bfloat16* khd  = (__hip_bfloat16*)(ws + 41 * MB);
  __hip_bfloat16* vtd  = (__hip_bfloat16*)(ws + 49 * MB);
  __hip_bfloat16* oc   = (__hip_bfloat16*)(ws + 57 * MB);

  prep<<<12288, 256, 0, stream>>>(q, k, v, mask, Wq, Wk, Wv, Wo, ws);
  proj_qkv<<<768, 256, 0, stream>>>(qb, kb, vb, Wcat, bq, bk, bv, qhd, khd, vtd);
  flash_attn<<<512, 256, 0, stream>>>(qhd, khd, vtd, mb2, oc);
  gemm_out<<<512, 256, 0, stream>>>(oc, Wob, bo, (float*)d_out);
}

// Round 10
// 238.154 us; speedup vs baseline: 1.0496x; 1.0016x over previous
//
#include <hip/hip_runtime.h>
#include <hip/hip_bf16.h>

// MultiHeadAttention: B=2, S=2048, D=1024, H=16, DK=64
// Round 18 = R17 resubmitted verbatim (R17's bench died with "MI355X
// container failed twice" — infra acquire error, no kernel signal; schedule
// re-audited: uniform barrier count, 3-buffer rotation race-free, ~140 VGPR).
// T15 lagged-PV pipeline in flash_attn: iteration t emits QK^T(t) ->
// PV(t-1) -> softmax(t); PV(t-1) (P kept in registers) is independent of
// QK^T(t) so both MFMA clusters pack the matrix pipe while softmax(t)'s
// exp2/cvt VALU work fills the issue gaps (m214v36: +7-11% on this
// structure). K/V in 3 LDS buffers (48KB, 2 blocks/CU), pbC[4] static-only
// indexing, cA/cB live across PV.
// prep (x8-vectorized) / proj_qkv / gemm_out unchanged from R16.
// Workspace: qb@0 kb@8 vb@16 Wcat@24(6M) Wob@30 mb@32 qhd@33 khd@41
//            vtd@49 oc@57  (MiB offsets)

using bf16x8 = __attribute__((ext_vector_type(8))) short;
using f32x4  = __attribute__((ext_vector_type(4))) float;
using f32x16 = __attribute__((ext_vector_type(16))) float;

constexpr int Bc = 2, Sc = 2048, Dc = 1024, Hc = 16, DKc = 64;
constexpr int Mc = Bc * Sc;  // 4096
#define QSCALE 0.18033688011112042f  // log2(e)/sqrt(DK), folded into Q proj

__device__ __forceinline__ void lds_load16(const void* g, void* l) {
  __builtin_amdgcn_global_load_lds(
      (const __attribute__((address_space(1))) unsigned int*)g,
      (__attribute__((address_space(3))) unsigned int*)l, 16, 0, 0);
}

#if __has_builtin(__builtin_amdgcn_exp2f)
__device__ __forceinline__ float exp2_fast(float x) { return __builtin_amdgcn_exp2f(x); }
#else
__device__ __forceinline__ float exp2_fast(float x) {
  float r;
  asm("v_exp_f32 %0, %1\n\ts_nop 0" : "=v"(r) : "v"(x));
  return r;
}
#endif

// pack two f32 to bf16x2 word (RNE) via HW cvt
__device__ __forceinline__ unsigned cvt_pk_bf16(float lo, float hi) {
  unsigned r;
  asm("v_cvt_pk_bf16_f32 %0, %1, %2" : "=v"(r) : "v"(lo), "v"(hi));
  return r;
}

// in-place half-swap: a' = [a.lo | b.lo(from lane-32)], b' = [a.hi | b.hi]
#define PSWAP(A, B) \
  asm volatile("v_permlane32_swap_b32 %0, %1" : "+v"(A), "+v"(B))

// RNE pack (epilogues + casts)
__device__ __forceinline__ unsigned pack2bf(float a, float b) {
  union { __hip_bfloat16 h; unsigned short s; } ua, ub;
  ua.h = __float2bfloat16(a);
  ub.h = __float2bfloat16(b);
  return (unsigned)ua.s | ((unsigned)ub.s << 16);
}

// ---------------- prep: fused casts + mask pack (x8 vectorized) -----------
__global__ void prep(const float* __restrict__ q, const float* __restrict__ k,
                     const float* __restrict__ v, const int* __restrict__ mask,
                     const float* __restrict__ Wq, const float* __restrict__ Wk,
                     const float* __restrict__ Wv, const float* __restrict__ Wo,
                     char* __restrict__ ws) {
  const size_t MB = 1024 * 1024;
  int blk = blockIdx.x;
  int tid = threadIdx.x;
  if (blk < 6144) {
    int which = blk >> 11;
    int i = (((blk & 2047) << 8) + tid) * 8;
    const float* s = which == 0 ? q : (which == 1 ? k : v);
    __hip_bfloat16* d = (__hip_bfloat16*)(ws + (size_t)which * 8 * MB);
    float4 x = *(const float4*)&s[i];
    float4 y = *(const float4*)&s[i + 4];
    uint4 pk = {pack2bf(x.x, x.y), pack2bf(x.z, x.w),
                pack2bf(y.x, y.y), pack2bf(y.z, y.w)};
    *(uint4*)&d[i] = pk;
  } else if (blk < 8192) {
    int bb = blk - 6144;
    int which = bb >> 9;
    int i = (((bb & 511) << 8) + tid) * 8;
    const float* s = which == 0 ? Wq : (which == 1 ? Wk : (which == 2 ? Wv : Wo));
    __hip_bfloat16* d = which < 3 ? (__hip_bfloat16*)(ws + (24 + 2 * which) * MB)
                                  : (__hip_bfloat16*)(ws + 30 * MB);
    float4 x = *(const float4*)&s[i];
    float4 y = *(const float4*)&s[i + 4];
    uint4 pk = {pack2bf(x.x, x.y), pack2bf(x.z, x.w),
                pack2bf(y.x, y.y), pack2bf(y.z, y.w)};
    *(uint4*)&d[i] = pk;
  } else {
    int blkm = blk - 8192;
    int i0 = ((blkm << 8) + tid) * 4;
    uint4 m = *(const uint4*)&mask[i0];
    unsigned nib = (m.x != 0 ? 1u : 0u) | (m.y != 0 ? 2u : 0u) |
                   (m.z != 0 ? 4u : 0u) | (m.w != 0 ? 8u : 0u);
    unsigned long long w = (unsigned long long)nib << (4 * (tid & 15));
    w |= __shfl_xor(w, 1);
    w |= __shfl_xor(w, 2);
    w |= __shfl_xor(w, 4);
    w |= __shfl_xor(w, 8);
    if ((tid & 15) == 0)
      ((unsigned long long*)(ws + 32 * MB))[(blkm << 4) + (tid >> 4)] = w;
  }
}

// ---------------- fused QKV projection (BK=32 dbuf, DMA both sides) -------
__global__ __launch_bounds__(256, 3) void proj_qkv(
    const __hip_bfloat16* __restrict__ qb, const __hip_bfloat16* __restrict__ kb,
    const __hip_bfloat16* __restrict__ vb, const __hip_bfloat16* __restrict__ Wcat,
    const float* __restrict__ bq, const float* __restrict__ bk,
    const float* __restrict__ bv, __hip_bfloat16* __restrict__ qhd,
    __hip_bfloat16* __restrict__ khd, __hip_bfloat16* __restrict__ vtd) {
  __shared__ __align__(16) __hip_bfloat16 As[2][128 * 32];  // W tiles, 8KB each
  __shared__ __align__(16) __hip_bfloat16 Bs[2][128 * 32];  // X tiles
  const int tid = threadIdx.x;
  const int f = blockIdx.x, g = f >> 3;
  const int m0 = ((f & 7) * 4 + g / 24) * 128;  // s block
  const int n0 = (g % 24) * 128;                // feature block (0..3072)
  const int which = n0 >> 10, nl0 = n0 & 1023;
  const __hip_bfloat16* X = which == 0 ? qb : (which == 1 ? kb : vb);
  const float* bias = which == 0 ? bq : (which == 1 ? bk : bv);
  const int w = tid >> 6, lane = tid & 63, ln = lane & 15, quad = lane >> 4;
  const int rl = w * 32 + (lane >> 2);
  const int sw8 = ((lane & 3) ^ ((lane >> 2) & 3)) * 8;
  const int aoff = (n0 + rl) * 1024 + sw8;
  const int boff = (m0 + rl) * 1024 + sw8;
  char* aDst = (char*)As + w * 2048 + lane * 16;
  char* bDst = (char*)Bs + w * 2048 + lane * 16;
  const int rkq = (quad ^ (ln & 3)) * 16;
  const int rA0 = ((w >> 1) * 64 + ln) * 64 + rkq;   // + i*1024
  const int rB0 = ((w & 1) * 64 + ln) * 64 + rkq;    // + j*1024
  f32x4 acc[4][4] = {};  // [i: feature 16-blk][j: s 16-blk]

#define PSTAGE(KO, BI)                                                        \
  {                                                                           \
    lds_load16(&Wcat[aoff + (KO)], aDst + (BI)*8192);                         \
    lds_load16(&Wcat[aoff + 16384 + (KO)], aDst + (BI)*8192 + 1024);          \
    lds_load16(&X[boff + (KO)], bDst + (BI)*8192);                            \
    lds_load16(&X[boff + 16384 + (KO)], bDst + (BI)*8192 + 1024);             \
  }

  PSTAGE(0, 0);
  if (which == 2) {
    for (int kb32 = 0; kb32 < 32; ++kb32) {
      const int bi = kb32 & 1;
      __syncthreads();
      if (kb32 < 31) PSTAGE((kb32 + 1) * 32, bi ^ 1);
      bf16x8 af[4], bf[4];
#pragma unroll
      for (int i = 0; i < 4; ++i)
        af[i] = *(bf16x8*)((char*)As + bi * 8192 + rA0 + i * 1024);
#pragma unroll
      for (int j = 0; j < 4; ++j)
        bf[j] = *(bf16x8*)((char*)Bs + bi * 8192 + rB0 + j * 1024);
#pragma unroll
      for (int i = 0; i < 4; ++i)
#pragma unroll
        for (int j = 0; j < 4; ++j)  // swapped: A=X -> C rows = s
          acc[i][j] = __builtin_amdgcn_mfma_f32_16x16x32_bf16(bf[j], af[i],
                                                              acc[i][j], 0, 0, 0);
    }
  } else {
    for (int kb32 = 0; kb32 < 32; ++kb32) {
      const int bi = kb32 & 1;
      __syncthreads();
      if (kb32 < 31) PSTAGE((kb32 + 1) * 32, bi ^ 1);
      bf16x8 af[4], bf[4];
#pragma unroll
      for (int i = 0; i < 4; ++i)
        af[i] = *(bf16x8*)((char*)As + bi * 8192 + rA0 + i * 1024);
#pragma unroll
      for (int j = 0; j < 4; ++j)
        bf[j] = *(bf16x8*)((char*)Bs + bi * 8192 + rB0 + j * 1024);
#pragma unroll
      for (int i = 0; i < 4; ++i)
#pragma unroll
        for (int j = 0; j < 4; ++j)  // A=W -> C rows = features
          acc[i][j] = __builtin_amdgcn_mfma_f32_16x16x32_bf16(af[i], bf[j],
                                                              acc[i][j], 0, 0, 0);
    }
  }

  const int wA = (w >> 1) * 64, wB = (w & 1) * 64;
  if (which == 2) {
#pragma unroll
    for (int i = 0; i < 4; ++i) {
      int nf = nl0 + wA + i * 16 + ln;
      int h = nf >> 6, dk = nf & 63;
      float bb = bias[nf];
#pragma unroll
      for (int j = 0; j < 4; ++j) {
        int sb = m0 + wB + j * 16 + quad * 4;
        int b = sb >> 11, s = sb & 2047;
        float vv[4] = {acc[i][j][0] + bb, acc[i][j][1] + bb,
                       acc[i][j][2] + bb, acc[i][j][3] + bb};
        uint2 pk = {pack2bf(vv[0], vv[1]), pack2bf(vv[2], vv[3])};
        *(uint2*)&vtd[(((size_t)(b * Hc + h) * DKc + dk) * Sc) + s] = pk;
      }
    }
  } else {
#pragma unroll
    for (int i = 0; i < 4; ++i) {
      int nfb = nl0 + wA + i * 16 + quad * 4;
      float4 b4 = *(const float4*)&bias[nfb];
      int h = nfb >> 6, dk0 = nfb & 63;
#pragma unroll
      for (int j = 0; j < 4; ++j) {
        int sg = m0 + wB + j * 16 + ln;
        int b = sg >> 11, s = sg & 2047;
        float vv[4] = {acc[i][j][0] + b4.x, acc[i][j][1] + b4.y,
                       acc[i][j][2] + b4.z, acc[i][j][3] + b4.w};
        if (which == 0) {
          uint2 pk = {pack2bf(vv[0] * QSCALE, vv[1] * QSCALE),
                      pack2bf(vv[2] * QSCALE, vv[3] * QSCALE)};
          *(uint2*)&qhd[(((size_t)(b * Hc + h) * Sc + s) * DKc) + dk0] = pk;
        } else {
          uint2 pk = {pack2bf(vv[0], vv[1]), pack2bf(vv[2], vv[3])};
          *(uint2*)&khd[(((size_t)(b * Hc + h) * Sc + s) * DKc) + dk0] = pk;
        }
      }
    }
  }
}

// ---------------- out projection (swapped): Y = oc @ Wo^T + bo ------------
__global__ __launch_bounds__(256, 2) void gemm_out(
    const __hip_bfloat16* __restrict__ X, const __hip_bfloat16* __restrict__ W,
    const float* __restrict__ bias, float* __restrict__ Y) {
  __shared__ __align__(16) __hip_bfloat16 As[2][64 * 64];   // Wo tile
  __shared__ __align__(16) __hip_bfloat16 Bs[2][128 * 64];  // oc tile
  const int tid = threadIdx.x;
  const int f = blockIdx.x, g = f >> 3;
  const int m0 = ((f & 7) * 4 + (g >> 4)) * 128;  // s block
  const int n0 = (g & 15) * 64;                    // feature block
  const int w = tid >> 6, lane = tid & 63, ln = lane & 15, quad = lane >> 4;
  const int wA = (w & 1) * 32, wB = (w >> 1) * 64;
  const int swz = ((lane & 7) ^ (lane >> 3)) * 8;
  const int rk0 = ln * 128 + ((quad ^ (ln & 7)) * 16);
  const int rk1 = ln * 128 + (((quad + 4) ^ (ln & 7)) * 16);
  const int aoff = (n0 + w * 16 + (lane >> 3)) * 1024 + swz;
  const int boff = (m0 + w * 32 + (lane >> 3)) * 1024 + swz;
  f32x4 acc[2][4] = {};

#define OSTAGE(KO, BI)                                                        \
  {                                                                           \
    _Pragma("unroll") for (int i = 0; i < 2; ++i)                             \
        lds_load16(&W[aoff + i * 8192 + (KO)],                                \
                   (char*)As[BI] + w * 2048 + lane * 16 + i * 1024);          \
    _Pragma("unroll") for (int i = 0; i < 4; ++i)                             \
        lds_load16(&X[boff + i * 8192 + (KO)],                                \
                   (char*)Bs[BI] + w * 4096 + lane * 16 + i * 1024);          \
  }

  OSTAGE(0, 0);
  for (int kb64 = 0; kb64 < 16; ++kb64) {
    const int bi = kb64 & 1;
    __syncthreads();
    if (kb64 + 1 < 16) OSTAGE((kb64 + 1) * 64, bi ^ 1);
    bf16x8 af[2][2], bf[4][2];
#pragma unroll
    for (int i = 0; i < 2; ++i) {
      af[i][0] = *(bf16x8*)((char*)As[bi] + wA * 128 + i * 2048 + rk0);
      af[i][1] = *(bf16x8*)((char*)As[bi] + wA * 128 + i * 2048 + rk1);
    }
#pragma unroll
    for (int j = 0; j < 4; ++j) {
      bf[j][0] = *(bf16x8*)((char*)Bs[bi] + wB * 128 + j * 2048 + rk0);
      bf[j][1] = *(bf16x8*)((char*)Bs[bi] + wB * 128 + j * 2048 + rk1);
    }
#pragma unroll
    for (int i = 0; i < 2; ++i)
#pragma unroll
      for (int j = 0; j < 4; ++j) {
        acc[i][j] = __builtin_amdgcn_mfma_f32_16x16x32_bf16(af[i][0], bf[j][0],
                                                            acc[i][j], 0, 0, 0);
        acc[i][j] = __builtin_amdgcn_mfma_f32_16x16x32_bf16(af[i][1], bf[j][1],
                                                            acc[i][j], 0, 0, 0);
      }
  }
#pragma unroll
  for (int i = 0; i < 2; ++i) {
    int nfb = n0 + wA + i * 16 + quad * 4;
    float4 b4 = *(const float4*)&bias[nfb];
#pragma unroll
    for (int j = 0; j < 4; ++j) {
      int sg = m0 + wB + j * 16 + ln;
      float4 st = {acc[i][j][0] + b4.x, acc[i][j][1] + b4.y,
                   acc[i][j][2] + b4.z, acc[i][j][3] + b4.w};
      *(float4*)&Y[(size_t)sg * Dc + nfb] = st;
    }
  }
}

// ---------------- flash attention (32x32, in-reg P, lagged PV) ------------
__global__ __launch_bounds__(256, 2) void flash_attn(
    const __hip_bfloat16* __restrict__ qh, const __hip_bfloat16* __restrict__ kh,
    const __hip_bfloat16* __restrict__ vt, const uint2* __restrict__ mb2,
    __hip_bfloat16* __restrict__ oc) {
  __shared__ __align__(16) char L[49152];  // K bufs 3x8K @0, V^T bufs 3x8K @24576
  const int tid = threadIdx.x;
  const int f = blockIdx.x, g = f >> 3;
  const int bh = (f & 7) * 4 + (g >> 4);  // 0..31
  const int q0 = (g & 15) * 128;
  const int b = bh >> 4, h = bh & 15;
  const int w = tid >> 6, lane = tid & 63, l31 = lane & 31, hi = lane >> 5;
  const size_t base = (size_t)bh * Sc * DKc;
  const __hip_bfloat16* khb = kh + base;
  const __hip_bfloat16* vtb = vt + base;
  const int qglob = q0 + w * 32 + l31;

  // Q B-fragments: B[d = dt*16 + hi*8 + j][q = l31]
  bf16x8 qf[4];
#pragma unroll
  for (int dt = 0; dt < 4; ++dt)
    qf[dt] = *(const bf16x8*)&qh[base + (size_t)qglob * 64 + dt * 16 + hi * 8];

  bf16x8 onesA;
#pragma unroll
  for (int i = 0; i < 8; ++i) onesA[i] = (short)0x3F80;  // bf16 1.0

  // DMA: linear LDS dest, pre-swizzled global src (slot s' holds d/k-slot
  // s'^(row&7)). K tile [64k][64d]; V^T tile [64d][64k].
  const int trow = tid >> 3, tcol = tid & 7;
  const int kbase = trow * 64 + ((tcol ^ (trow & 7)) * 8);    // elements
  const int vbase = trow * 2048 + ((tcol ^ (trow & 7)) * 8);  // elements
  char* Ld = L + tid * 16;

  const int rowb = l31 * 128;
  const int xs = lane & 7;

  f32x16 Oacc0 = {}, Oacc1 = {}, lacc = {};
  bf16x8 pbC[4];   // P fragments of the PREVIOUS tile (static indices only)
  f32x16 cA, cB;   // QK^T results, live across PV

// stage tile T into buffer byte-offset BOFF (runtime ok)
#define STAGE_OFF(BOFF, T)                                                    \
  {                                                                           \
    lds_load16(khb + kbase + (T)*4096,        Ld + (BOFF));                   \
    lds_load16(khb + kbase + (T)*4096 + 2048, Ld + (BOFF) + 4096);            \
    lds_load16(vtb + vbase + (T)*64,          Ld + 24576 + (BOFF));           \
    lds_load16(vtb + vbase + (T)*64 + 65536,  Ld + 24576 + (BOFF) + 4096);    \
  }

// QK^T of one 32-k subtile into CV (4-deep MFMA chain)
#define QKT_SUB(BOFF, SUB, CV)                                                \
  {                                                                           \
    bf16x8 kf0 = *(bf16x8*)(L + (BOFF) + (SUB)*4096 + rowb + (((0 + hi) ^ xs) * 16)); \
    bf16x8 kf1 = *(bf16x8*)(L + (BOFF) + (SUB)*4096 + rowb + (((2 + hi) ^ xs) * 16)); \
    bf16x8 kf2 = *(bf16x8*)(L + (BOFF) + (SUB)*4096 + rowb + (((4 + hi) ^ xs) * 16)); \
    bf16x8 kf3 = *(bf16x8*)(L + (BOFF) + (SUB)*4096 + rowb + (((6 + hi) ^ xs) * 16)); \
    f32x16 zz_ = {};                                                          \
    CV = __builtin_amdgcn_mfma_f32_32x32x16_bf16(kf0, qf[0], zz_, 0, 0, 0);   \
    CV = __builtin_amdgcn_mfma_f32_32x32x16_bf16(kf1, qf[1], CV, 0, 0, 0);    \
    CV = __builtin_amdgcn_mfma_f32_32x32x16_bf16(kf2, qf[2], CV, 0, 0, 0);    \
    CV = __builtin_amdgcn_mfma_f32_32x32x16_bf16(kf3, qf[3], CV, 0, 0, 0);    \
  }

// masked exp2 softmax of CV -> two bf16x8 B-fragments (cvt_pk + permlane)
#define SM_SUB(CV, MW, PB0, PB1)                                              \
  {                                                                           \
    unsigned shm = (MW) >> (hi * 4);                                          \
    float p[16];                                                              \
    _Pragma("unroll") for (int r = 0; r < 16; ++r) {                          \
      unsigned tg = shm >> (8 * (r >> 2));                                    \
      float e = exp2_fast(CV[r]);                                             \
      p[r] = (tg & (1u << (r & 3))) ? e : 0.f;                                \
    }                                                                         \
    unsigned w0 = cvt_pk_bf16(p[0], p[1]),   w1 = cvt_pk_bf16(p[2], p[3]);    \
    unsigned w2 = cvt_pk_bf16(p[4], p[5]),   w3 = cvt_pk_bf16(p[6], p[7]);    \
    unsigned w4 = cvt_pk_bf16(p[8], p[9]),   w5 = cvt_pk_bf16(p[10], p[11]);  \
    unsigned w6 = cvt_pk_bf16(p[12], p[13]), w7 = cvt_pk_bf16(p[14], p[15]);  \
    PSWAP(w0, w2); PSWAP(w1, w3); PSWAP(w4, w6); PSWAP(w5, w7);               \
    { union { unsigned u[4]; bf16x8 v; } tt_;                                 \
      tt_.u[0] = w0; tt_.u[1] = w1; tt_.u[2] = w2; tt_.u[3] = w3;             \
      PB0 = tt_.v; }                                                          \
    { union { unsigned u[4]; bf16x8 v; } tt_;                                 \
      tt_.u[0] = w4; tt_.u[1] = w5; tt_.u[2] = w6; tt_.u[3] = w7;             \
      PB1 = tt_.v; }                                                          \
  }

// PV + l of the PREVIOUS tile (reads pbC + V buf at byte-off VOFF)
#define PV_CLUSTER(VOFF)                                                      \
  {                                                                           \
    __builtin_amdgcn_s_setprio(1);                                            \
    _Pragma("unroll") for (int kt = 0; kt < 4; ++kt) {                        \
      bf16x8 vf0 = *(bf16x8*)(L + 24576 + (VOFF) + rowb + (((kt * 2 + hi) ^ xs) * 16)); \
      bf16x8 vf1 = *(bf16x8*)(L + 24576 + (VOFF) + 4096 + rowb + (((kt * 2 + hi) ^ xs) * 16)); \
      lacc  = __builtin_amdgcn_mfma_f32_32x32x16_bf16(onesA, pbC[kt], lacc, 0, 0, 0); \
      Oacc0 = __builtin_amdgcn_mfma_f32_32x32x16_bf16(vf0, pbC[kt], Oacc0, 0, 0, 0);  \
      Oacc1 = __builtin_amdgcn_mfma_f32_32x32x16_bf16(vf1, pbC[kt], Oacc1, 0, 0, 0);  \
    }                                                                         \
    __builtin_amdgcn_s_setprio(0);                                            \
  }

  const uint2* mrow = mb2 + (size_t)qglob * 32;
  uint2 mbC = mrow[0];
  STAGE_OFF(0, 0);           // tile 0 -> buf 0
  __syncthreads();           // drain tile 0
  uint2 mbN = mrow[1];
  STAGE_OFF(8192, 1);        // tile 1 -> buf 1 (drains at loop-top t=1)
  // peeled iter 0: QK^T(0) + softmax(0) -> pbC (no PV yet)
  __builtin_amdgcn_s_setprio(1);
  QKT_SUB(0, 0, cA);
  QKT_SUB(0, 1, cB);
  __builtin_amdgcn_s_setprio(0);
  SM_SUB(cA, mbC.x, pbC[0], pbC[1]);
  SM_SUB(cB, mbC.y, pbC[2], pbC[3]);
  mbC = mbN;

  int curo = 8192, prevo = 0;  // byte offsets of tile t / tile t-1 buffers
  for (int t = 1; t < 32; ++t) {
    __syncthreads();  // drains STAGE(t); all waves finished PV(t-2)
    if (t < 31) {
      mbN = mrow[t + 1];
      int nxto = curo + 8192; if (nxto == 24576) nxto = 0;
      STAGE_OFF(nxto, t + 1);  // overwrites buf of tile t-2 (reads done)
    }
    __builtin_amdgcn_s_setprio(1);
    QKT_SUB(curo, 0, cA);   // MFMA cluster 1 (tile t)
    QKT_SUB(curo, 1, cB);
    __builtin_amdgcn_s_setprio(0);
    PV_CLUSTER(prevo);      // MFMA cluster 2 (tile t-1, independent of cA/cB)
    SM_SUB(cA, mbC.x, pbC[0], pbC[1]);  // VALU, overlaps PV on the other pipe
    SM_SUB(cB, mbC.y, pbC[2], pbC[3]);
    prevo = curo;
    curo += 8192; if (curo == 24576) curo = 0;
    mbC = mbN;
  }
  PV_CLUSTER(prevo);  // drain: PV(31) (V buf already synced at loop top t=31)

  // ---- epilogue: all state in registers; direct packed stores ----
  float linv = 1.f / fmaxf(lacc[0], 1e-30f);
  const size_t obase = (size_t)(b * Sc + qglob) * Dc + h * 64;
#pragma unroll
  for (int gq = 0; gq < 4; ++gq) {
    int d0 = gq * 8 + hi * 4;
    uint2 pk0 = {pack2bf(Oacc0[4 * gq] * linv, Oacc0[4 * gq + 1] * linv),
                 pack2bf(Oacc0[4 * gq + 2] * linv, Oacc0[4 * gq + 3] * linv)};
    *(uint2*)&oc[obase + d0] = pk0;
    uint2 pk1 = {pack2bf(Oacc1[4 * gq] * linv, Oacc1[4 * gq + 1] * linv),
                 pack2bf(Oacc1[4 * gq + 2] * linv, Oacc1[4 * gq + 3] * linv)};
    *(uint2*)&oc[obase + 32 + d0] = pk1;
  }
#undef STAGE_OFF
#undef QKT_SUB
#undef SM_SUB
#undef PV_CLUSTER
}

extern "C" void kernel_launch(void* const* d_in, const int* in_sizes, int n_in,
                              void* d_out, int out_size, void* d_ws, size_t ws_size,
                              hipStream_t stream) {
  const float* q  = (const float*)d_in[0];
  const float* k  = (const float*)d_in[1];
  const float* v  = (const float*)d_in[2];
  const int* mask = (const int*)d_in[3];
  const float* Wq = (const float*)d_in[4];
  const float* bq = (const float*)d_in[5];
  const float* Wk = (const float*)d_in[6];
  const float* bk = (const float*)d_in[7];
  const float* Wv = (const float*)d_in[8];
  const float* bv = (const float*)d_in[9];
  const float* Wo = (const float*)d_in[10];
  const float* bo = (const float*)d_in[11];

  char* ws = (char*)d_ws;
  const size_t MB = 1024 * 1024;
  __hip_bfloat16* qb   = (__hip_bfloat16*)(ws + 0 * MB);
  __hip_bfloat16* kb   = (__hip_bfloat16*)(ws + 8 * MB);
  __hip_bfloat16* vb   = (__hip_bfloat16*)(ws + 16 * MB);
  __hip_bfloat16* Wcat = (__hip_bfloat16*)(ws + 24 * MB);  // Wq|Wk|Wv
  __hip_bfloat16* Wob  = (__hip_bfloat16*)(ws + 30 * MB);
  uint2*          mb2  = (uint2*)(ws + 32 * MB);
  __hip_bfloat16* qhd  = (__hip_bfloat16*)(ws + 33 * MB);
  __hip_bfloat16* khd  = (__hip_bfloat16*)(ws + 41 * MB);
  __hip_bfloat16* vtd  = (__hip_bfloat16*)(ws + 49 * MB);
  __hip_bfloat16* oc   = (__hip_bfloat16*)(ws + 57 * MB);

  prep<<<12288, 256, 0, stream>>>(q, k, v, mask, Wq, Wk, Wv, Wo, ws);
  proj_qkv<<<768, 256, 0, stream>>>(qb, kb, vb, Wcat, bq, bk, bv, qhd, khd, vtd);
  flash_attn<<<512, 256, 0, stream>>>(qhd, khd, vtd, mb2, oc);
  gemm_out<<<512, 256, 0, stream>>>(oc, Wob, bo, (float*)d_out);
}